// Round 3
// baseline (272.211 us; speedup 1.0000x reference)
//
#include <hip/hip_runtime.h>
#include <hip/hip_bf16.h>

// Problem constants
constexpr int BATCH = 8192;   // M
constexpr int THEADS = 137;   // number of predict heads (grid.y)
constexpr int DFEA = 384;     // reduction dim of GEMM1
constexpr int KHID = 128;     // per-head hidden width
constexpr float EPS_BN = 1e-5f;
constexpr float SLOPE = 0.01f;

typedef __attribute__((ext_vector_type(8))) short bf16x8;   // 8 bf16 = 4 VGPRs
typedef __attribute__((ext_vector_type(4))) float f32x4;

__device__ __forceinline__ short cvt_bf16(float x) {
    __hip_bfloat16 b = __float2bfloat16(x);
    return *(short*)&b;
}

// load 8 consecutive fp32, convert to packed bf16x8
__device__ __forceinline__ bf16x8 load8_cvt(const float* __restrict__ g) {
    f32x4 lo = *(const f32x4*)g;
    f32x4 hi = *(const f32x4*)(g + 4);
    bf16x8 r;
    r[0] = cvt_bf16(lo[0]); r[1] = cvt_bf16(lo[1]);
    r[2] = cvt_bf16(lo[2]); r[3] = cvt_bf16(lo[3]);
    r[4] = cvt_bf16(hi[0]); r[5] = cvt_bf16(hi[1]);
    r[6] = cvt_bf16(hi[2]); r[7] = cvt_bf16(hi[3]);
    return r;
}

__global__ __launch_bounds__(256) void fused_heads(
    const float* __restrict__ f,      // [8192, 384]
    const float* __restrict__ W1,     // [137*128, 384] (row n = t*128+k, D-contig)
    const float* __restrict__ b1,     // [137*128]
    const float* __restrict__ gmm,    // gamma [137*128]
    const float* __restrict__ bta,    // beta  [137*128]
    const float* __restrict__ rmean,  // [137*128]
    const float* __restrict__ rvar,   // [137*128]
    const float* __restrict__ W2,     // [137*128]
    const float* __restrict__ b2,     // [137]
    float* __restrict__ out)          // [8192, 137]
{
    // 128x128 tile, BK=32, bf16 LDS tiles (converted during staging).
    __shared__ __attribute__((aligned(16))) __hip_bfloat16 As[128 * 32];
    __shared__ __attribute__((aligned(16))) __hip_bfloat16 Bs[128 * 32];
    __shared__ float red[2][128];

    const int tid  = threadIdx.x;
    const int lane = tid & 63;
    const int wave = tid >> 6;
    const int wm = wave >> 1;       // wave row (0..1) -> 64 rows of M
    const int wn = wave & 1;        // wave col (0..1) -> 64 cols of N
    const int m0 = blockIdx.x * 128;
    const int t  = blockIdx.y;      // head index
    const int n0 = t * KHID;        // first of the 128 columns of this head

    // Staging map: 128 rows x 32 cols bf16 = 512 chunks of 8 elems; 256 threads x 2.
    // chunk li -> LDS elements [li*8, li*8+8), global (row = li>>2, col = (li&3)*8)
    const int li0 = tid, li1 = tid + 256;
    const int r0 = li0 >> 2, c0 = (li0 & 3) * 8;
    const int r1 = li1 >> 2, c1 = (li1 & 3) * 8;
    const float* gA0 = f  + (size_t)(m0 + r0) * DFEA + c0;
    const float* gA1 = f  + (size_t)(m0 + r1) * DFEA + c1;
    const float* gB0 = W1 + (size_t)(n0 + r0) * DFEA + c0;
    const float* gB1 = W1 + (size_t)(n0 + r1) * DFEA + c1;

    const int row16 = lane & 15;    // fragment row/col within 16-tile
    const int quad  = lane >> 4;    // k-group select

    f32x4 acc[4][4];
    #pragma unroll
    for (int i = 0; i < 4; ++i)
        #pragma unroll
        for (int j = 0; j < 4; ++j)
            acc[i][j] = (f32x4){0.f, 0.f, 0.f, 0.f};

    #pragma unroll 1
    for (int kt = 0; kt < DFEA / 32; ++kt) {
        const int k0 = kt * 32;
        // global fp32 -> registers -> bf16 pack
        bf16x8 va0 = load8_cvt(gA0 + k0);
        bf16x8 va1 = load8_cvt(gA1 + k0);
        bf16x8 vb0 = load8_cvt(gB0 + k0);
        bf16x8 vb1 = load8_cvt(gB1 + k0);

        __syncthreads();   // all waves done reading LDS from previous iteration
        *(bf16x8*)&As[li0 * 8] = va0;
        *(bf16x8*)&As[li1 * 8] = va1;
        *(bf16x8*)&Bs[li0 * 8] = vb0;
        *(bf16x8*)&Bs[li1 * 8] = vb1;
        __syncthreads();   // tiles valid

        bf16x8 af[4], bf[4];
        #pragma unroll
        for (int i = 0; i < 4; ++i)
            af[i] = *(const bf16x8*)&As[(wm * 64 + i * 16 + row16) * 32 + quad * 8];
        #pragma unroll
        for (int i = 0; i < 4; ++i)
            bf[i] = *(const bf16x8*)&Bs[(wn * 64 + i * 16 + row16) * 32 + quad * 8];

        #pragma unroll
        for (int ai = 0; ai < 4; ++ai)
            #pragma unroll
            for (int bi = 0; bi < 4; ++bi)
                acc[ai][bi] = __builtin_amdgcn_mfma_f32_16x16x32_bf16(
                    af[ai], bf[bi], acc[ai][bi], 0, 0, 0);
    }

    // ---- fused epilogue: BN (eval) + LeakyReLU + dot with W2 ----
    float s[4], cc[4], w2v[4];
    #pragma unroll
    for (int bi = 0; bi < 4; ++bi) {
        const int n = n0 + wn * 64 + bi * 16 + row16;   // this lane's column
        const float sv = gmm[n] * rsqrtf(rvar[n] + EPS_BN);
        s[bi]   = sv;
        cc[bi]  = bta[n] + (b1[n] - rmean[n]) * sv;
        w2v[bi] = W2[n];
    }

    float p[4][4];
    #pragma unroll
    for (int ai = 0; ai < 4; ++ai)
        #pragma unroll
        for (int r = 0; r < 4; ++r) {
            float a = 0.f;
            #pragma unroll
            for (int bi = 0; bi < 4; ++bi) {
                float y = acc[ai][bi][r] * s[bi] + cc[bi];
                y = (y >= 0.f) ? y : SLOPE * y;     // LeakyReLU
                a += y * w2v[bi];
            }
            p[ai][r] = a;
        }

    // reduce across the 16 column-lanes (C/D: col = lane&15)
    #pragma unroll
    for (int mask = 1; mask <= 8; mask <<= 1)
        #pragma unroll
        for (int ai = 0; ai < 4; ++ai)
            #pragma unroll
            for (int r = 0; r < 4; ++r)
                p[ai][r] += __shfl_xor(p[ai][r], mask);

    // lane with col 0 of each quad writes rows: row = ai*16 + quad*4 + r
    if (row16 == 0) {
        #pragma unroll
        for (int ai = 0; ai < 4; ++ai)
            #pragma unroll
            for (int r = 0; r < 4; ++r)
                red[wn][wm * 64 + ai * 16 + quad * 4 + r] = p[ai][r];
    }
    __syncthreads();

    if (tid < 128) {
        const float v = red[0][tid] + red[1][tid] + b2[t];
        out[(size_t)(m0 + tid) * THEADS + t] = v;
    }
}

extern "C" void kernel_launch(void* const* d_in, const int* in_sizes, int n_in,
                              void* d_out, int out_size, void* d_ws, size_t ws_size,
                              hipStream_t stream) {
    (void)in_sizes; (void)n_in; (void)d_ws; (void)ws_size; (void)out_size;
    const float* f     = (const float*)d_in[0];
    const float* W1    = (const float*)d_in[1];
    const float* b1    = (const float*)d_in[2];
    const float* gmm   = (const float*)d_in[3];
    const float* bta   = (const float*)d_in[4];
    const float* rmean = (const float*)d_in[5];
    const float* rvar  = (const float*)d_in[6];
    const float* W2    = (const float*)d_in[7];
    const float* b2    = (const float*)d_in[8];
    float* out = (float*)d_out;

    dim3 grid(BATCH / 128, THEADS);
    fused_heads<<<grid, 256, 0, stream>>>(f, W1, b1, gmm, bta, rmean, rvar, W2, b2, out);
}

// Round 4
// 261.954 us; speedup vs baseline: 1.0392x; 1.0392x over previous
//
#include <hip/hip_runtime.h>
#include <hip/hip_bf16.h>

// Problem constants
constexpr int BATCH = 8192;   // M
constexpr int THEADS = 137;   // number of predict heads (grid.y)
constexpr int DFEA = 384;     // reduction dim of GEMM1
constexpr int KHID = 128;     // per-head hidden width
constexpr float EPS_BN = 1e-5f;
constexpr float SLOPE = 0.01f;

constexpr size_t N_F  = (size_t)BATCH * DFEA;          // 3,145,728
constexpr size_t N_W1 = (size_t)THEADS * KHID * DFEA;  // 6,733,824
constexpr size_t WS_NEED = (N_F + N_W1) * sizeof(__hip_bfloat16);

typedef __attribute__((ext_vector_type(8))) short bf16x8;   // 8 bf16 = 4 VGPRs
typedef __attribute__((ext_vector_type(4))) float f32x4;

__device__ __forceinline__ short cvt_bf16(float x) {
    __hip_bfloat16 b = __float2bfloat16(x);
    return *(short*)&b;
}

__device__ __forceinline__ bf16x8 load8_cvt(const float* __restrict__ g) {
    f32x4 lo = *(const f32x4*)g;
    f32x4 hi = *(const f32x4*)(g + 4);
    bf16x8 r;
    r[0] = cvt_bf16(lo[0]); r[1] = cvt_bf16(lo[1]);
    r[2] = cvt_bf16(lo[2]); r[3] = cvt_bf16(lo[3]);
    r[4] = cvt_bf16(hi[0]); r[5] = cvt_bf16(hi[1]);
    r[6] = cvt_bf16(hi[2]); r[7] = cvt_bf16(hi[3]);
    return r;
}

__device__ __forceinline__ void gload16(const void* g, void* s) {
    // async global->LDS, 16B/lane; HW dest = readfirstlane(base) + lane*16
    __builtin_amdgcn_global_load_lds((const __attribute__((address_space(1))) void*)g,
                                     (__attribute__((address_space(3))) void*)s,
                                     16, 0, 0);
}

// ---------------- pre-pass: fp32 -> bf16 bulk convert ----------------
__global__ __launch_bounds__(256) void cvt_pass(const float* __restrict__ in,
                                                __hip_bfloat16* __restrict__ out,
                                                int n8) {
    int i = blockIdx.x * 256 + threadIdx.x;
    if (i < n8)
        *(bf16x8*)(out + (size_t)i * 8) = load8_cvt(in + (size_t)i * 8);
}

// ---------------- main fused kernel (bf16 inputs via ws) ----------------
__global__ __launch_bounds__(256) void fused_heads_bf16(
    const __hip_bfloat16* __restrict__ fb,     // [8192, 384] bf16
    const __hip_bfloat16* __restrict__ W1b,    // [137*128, 384] bf16
    const float* __restrict__ b1,
    const float* __restrict__ gmm,
    const float* __restrict__ bta,
    const float* __restrict__ rmean,
    const float* __restrict__ rvar,
    const float* __restrict__ W2,
    const float* __restrict__ b2,
    float* __restrict__ out)                   // [8192, 137]
{
    __shared__ __attribute__((aligned(16))) __hip_bfloat16 As[128 * 32];
    __shared__ __attribute__((aligned(16))) __hip_bfloat16 Bs[128 * 32];
    __shared__ float red[2][128];

    const int tid  = threadIdx.x;
    const int lane = tid & 63;
    const int wave = tid >> 6;
    const int wm = wave >> 1;
    const int wn = wave & 1;
    const int m0 = blockIdx.x * 128;
    const int t  = blockIdx.y;
    const int n0 = t * KHID;

    // staging: 128x32 bf16 = 512 chunks of 16B per tile; 2 chunks/thread/tile
    const int li0 = tid, li1 = tid + 256;
    const int r0 = li0 >> 2, c0 = (li0 & 3) * 8;
    const int r1 = li1 >> 2, c1 = (li1 & 3) * 8;
    const __hip_bfloat16* gA0 = fb  + (size_t)(m0 + r0) * DFEA + c0;
    const __hip_bfloat16* gA1 = fb  + (size_t)(m0 + r1) * DFEA + c1;
    const __hip_bfloat16* gB0 = W1b + (size_t)(n0 + r0) * DFEA + c0;
    const __hip_bfloat16* gB1 = W1b + (size_t)(n0 + r1) * DFEA + c1;

    const int row16 = lane & 15;
    const int quad  = lane >> 4;

    f32x4 acc[4][4];
    #pragma unroll
    for (int i = 0; i < 4; ++i)
        #pragma unroll
        for (int j = 0; j < 4; ++j)
            acc[i][j] = (f32x4){0.f, 0.f, 0.f, 0.f};

    #pragma unroll 1
    for (int kt = 0; kt < DFEA / 32; ++kt) {
        const int k0 = kt * 32;
        gload16(gA0 + k0, &As[li0 * 8]);
        gload16(gA1 + k0, &As[li1 * 8]);
        gload16(gB0 + k0, &Bs[li0 * 8]);
        gload16(gB1 + k0, &Bs[li1 * 8]);
        __syncthreads();   // drains vmcnt -> tiles valid

        bf16x8 af[4], bfr[4];
        #pragma unroll
        for (int i = 0; i < 4; ++i)
            af[i] = *(const bf16x8*)&As[(wm * 64 + i * 16 + row16) * 32 + quad * 8];
        #pragma unroll
        for (int i = 0; i < 4; ++i)
            bfr[i] = *(const bf16x8*)&Bs[(wn * 64 + i * 16 + row16) * 32 + quad * 8];

        #pragma unroll
        for (int ai = 0; ai < 4; ++ai)
            #pragma unroll
            for (int bi = 0; bi < 4; ++bi)
                acc[ai][bi] = __builtin_amdgcn_mfma_f32_16x16x32_bf16(
                    af[ai], bfr[bi], acc[ai][bi], 0, 0, 0);
        __syncthreads();   // all reads done before next overwrite
    }

    // ---- fused epilogue ----
    float s[4], cc[4], w2v[4];
    #pragma unroll
    for (int bi = 0; bi < 4; ++bi) {
        const int n = n0 + wn * 64 + bi * 16 + row16;
        const float sv = gmm[n] * rsqrtf(rvar[n] + EPS_BN);
        s[bi]   = sv;
        cc[bi]  = bta[n] + (b1[n] - rmean[n]) * sv;
        w2v[bi] = W2[n];
    }

    float p[4][4];
    #pragma unroll
    for (int ai = 0; ai < 4; ++ai)
        #pragma unroll
        for (int r = 0; r < 4; ++r) {
            float a = 0.f;
            #pragma unroll
            for (int bi = 0; bi < 4; ++bi) {
                float y = acc[ai][bi][r] * s[bi] + cc[bi];
                y = (y >= 0.f) ? y : SLOPE * y;
                a += y * w2v[bi];
            }
            p[ai][r] = a;
        }

    #pragma unroll
    for (int mask = 1; mask <= 8; mask <<= 1)
        #pragma unroll
        for (int ai = 0; ai < 4; ++ai)
            #pragma unroll
            for (int r = 0; r < 4; ++r)
                p[ai][r] += __shfl_xor(p[ai][r], mask);

    if (row16 == 0) {
        #pragma unroll
        for (int ai = 0; ai < 4; ++ai)
            #pragma unroll
            for (int r = 0; r < 4; ++r)
                red[wn][wm * 64 + ai * 16 + quad * 4 + r] = p[ai][r];
    }
    __syncthreads();

    if (tid < 128) {
        const float v = red[0][tid] + red[1][tid] + b2[t];
        out[(size_t)(m0 + tid) * THEADS + t] = v;
    }
}

// ---------------- fallback: direct fp32 path (round-3 kernel) ----------------
__global__ __launch_bounds__(256) void fused_heads_f32(
    const float* __restrict__ f, const float* __restrict__ W1,
    const float* __restrict__ b1, const float* __restrict__ gmm,
    const float* __restrict__ bta, const float* __restrict__ rmean,
    const float* __restrict__ rvar, const float* __restrict__ W2,
    const float* __restrict__ b2, float* __restrict__ out)
{
    __shared__ __attribute__((aligned(16))) __hip_bfloat16 As[128 * 32];
    __shared__ __attribute__((aligned(16))) __hip_bfloat16 Bs[128 * 32];
    __shared__ float red[2][128];

    const int tid  = threadIdx.x;
    const int lane = tid & 63;
    const int wave = tid >> 6;
    const int wm = wave >> 1, wn = wave & 1;
    const int m0 = blockIdx.x * 128;
    const int t  = blockIdx.y;
    const int n0 = t * KHID;

    const int li0 = tid, li1 = tid + 256;
    const int r0 = li0 >> 2, c0 = (li0 & 3) * 8;
    const int r1 = li1 >> 2, c1 = (li1 & 3) * 8;
    const float* gA0 = f  + (size_t)(m0 + r0) * DFEA + c0;
    const float* gA1 = f  + (size_t)(m0 + r1) * DFEA + c1;
    const float* gB0 = W1 + (size_t)(n0 + r0) * DFEA + c0;
    const float* gB1 = W1 + (size_t)(n0 + r1) * DFEA + c1;

    const int row16 = lane & 15, quad = lane >> 4;

    f32x4 acc[4][4];
    #pragma unroll
    for (int i = 0; i < 4; ++i)
        #pragma unroll
        for (int j = 0; j < 4; ++j)
            acc[i][j] = (f32x4){0.f, 0.f, 0.f, 0.f};

    #pragma unroll 1
    for (int kt = 0; kt < DFEA / 32; ++kt) {
        const int k0 = kt * 32;
        bf16x8 va0 = load8_cvt(gA0 + k0);
        bf16x8 va1 = load8_cvt(gA1 + k0);
        bf16x8 vb0 = load8_cvt(gB0 + k0);
        bf16x8 vb1 = load8_cvt(gB1 + k0);
        __syncthreads();
        *(bf16x8*)&As[li0 * 8] = va0;
        *(bf16x8*)&As[li1 * 8] = va1;
        *(bf16x8*)&Bs[li0 * 8] = vb0;
        *(bf16x8*)&Bs[li1 * 8] = vb1;
        __syncthreads();

        bf16x8 af[4], bfr[4];
        #pragma unroll
        for (int i = 0; i < 4; ++i)
            af[i] = *(const bf16x8*)&As[(wm * 64 + i * 16 + row16) * 32 + quad * 8];
        #pragma unroll
        for (int i = 0; i < 4; ++i)
            bfr[i] = *(const bf16x8*)&Bs[(wn * 64 + i * 16 + row16) * 32 + quad * 8];
        #pragma unroll
        for (int ai = 0; ai < 4; ++ai)
            #pragma unroll
            for (int bi = 0; bi < 4; ++bi)
                acc[ai][bi] = __builtin_amdgcn_mfma_f32_16x16x32_bf16(
                    af[ai], bfr[bi], acc[ai][bi], 0, 0, 0);
    }

    float s[4], cc[4], w2v[4];
    #pragma unroll
    for (int bi = 0; bi < 4; ++bi) {
        const int n = n0 + wn * 64 + bi * 16 + row16;
        const float sv = gmm[n] * rsqrtf(rvar[n] + EPS_BN);
        s[bi] = sv;
        cc[bi] = bta[n] + (b1[n] - rmean[n]) * sv;
        w2v[bi] = W2[n];
    }
    float p[4][4];
    #pragma unroll
    for (int ai = 0; ai < 4; ++ai)
        #pragma unroll
        for (int r = 0; r < 4; ++r) {
            float a = 0.f;
            #pragma unroll
            for (int bi = 0; bi < 4; ++bi) {
                float y = acc[ai][bi][r] * s[bi] + cc[bi];
                y = (y >= 0.f) ? y : SLOPE * y;
                a += y * w2v[bi];
            }
            p[ai][r] = a;
        }
    #pragma unroll
    for (int mask = 1; mask <= 8; mask <<= 1)
        #pragma unroll
        for (int ai = 0; ai < 4; ++ai)
            #pragma unroll
            for (int r = 0; r < 4; ++r)
                p[ai][r] += __shfl_xor(p[ai][r], mask);
    if (row16 == 0) {
        #pragma unroll
        for (int ai = 0; ai < 4; ++ai)
            #pragma unroll
            for (int r = 0; r < 4; ++r)
                red[wn][wm * 64 + ai * 16 + quad * 4 + r] = p[ai][r];
    }
    __syncthreads();
    if (tid < 128)
        out[(size_t)(m0 + tid) * THEADS + t] = red[0][tid] + red[1][tid] + b2[t];
}

extern "C" void kernel_launch(void* const* d_in, const int* in_sizes, int n_in,
                              void* d_out, int out_size, void* d_ws, size_t ws_size,
                              hipStream_t stream) {
    (void)in_sizes; (void)n_in; (void)out_size;
    const float* f     = (const float*)d_in[0];
    const float* W1    = (const float*)d_in[1];
    const float* b1    = (const float*)d_in[2];
    const float* gmm   = (const float*)d_in[3];
    const float* bta   = (const float*)d_in[4];
    const float* rmean = (const float*)d_in[5];
    const float* rvar  = (const float*)d_in[6];
    const float* W2    = (const float*)d_in[7];
    const float* b2    = (const float*)d_in[8];
    float* out = (float*)d_out;

    dim3 grid(BATCH / 128, THEADS);
    if (ws_size >= WS_NEED) {
        __hip_bfloat16* fb  = (__hip_bfloat16*)d_ws;
        __hip_bfloat16* W1b = fb + N_F;
        cvt_pass<<<(int)(N_F  / 8 + 255) / 256, 256, 0, stream>>>(f,  fb,  (int)(N_F  / 8));
        cvt_pass<<<(int)(N_W1 / 8 + 255) / 256, 256, 0, stream>>>(W1, W1b, (int)(N_W1 / 8));
        fused_heads_bf16<<<grid, 256, 0, stream>>>(fb, W1b, b1, gmm, bta, rmean, rvar, W2, b2, out);
    } else {
        fused_heads_f32<<<grid, 256, 0, stream>>>(f, W1, b1, gmm, bta, rmean, rvar, W2, b2, out);
    }
}

// Round 5
// 220.760 us; speedup vs baseline: 1.2331x; 1.1866x over previous
//
#include <hip/hip_runtime.h>
#include <hip/hip_bf16.h>

// Problem constants
constexpr int BATCH = 8192;   // M
constexpr int THEADS = 137;   // number of predict heads (grid.y)
constexpr int DFEA = 384;     // reduction dim of GEMM1
constexpr int KHID = 128;     // per-head hidden width
constexpr float EPS_BN = 1e-5f;
constexpr float SLOPE = 0.01f;

constexpr size_t N_F  = (size_t)BATCH * DFEA;          // 3,145,728
constexpr size_t N_W1 = (size_t)THEADS * KHID * DFEA;  // 6,733,824
constexpr size_t WS_NEED = (N_F + N_W1) * sizeof(__hip_bfloat16);
constexpr int C_F8 = (int)(N_F / 8);                   // 393,216
constexpr int C_T8 = (int)((N_F + N_W1) / 8);          // 1,234,944

typedef __attribute__((ext_vector_type(8))) short bf16x8;   // 8 bf16 = 4 VGPRs
typedef __attribute__((ext_vector_type(4))) float f32x4;

__device__ __forceinline__ short cvt_bf16(float x) {
    __hip_bfloat16 b = __float2bfloat16(x);
    return *(short*)&b;
}

__device__ __forceinline__ bf16x8 load8_cvt(const float* __restrict__ g) {
    f32x4 lo = *(const f32x4*)g;
    f32x4 hi = *(const f32x4*)(g + 4);
    bf16x8 r;
    r[0] = cvt_bf16(lo[0]); r[1] = cvt_bf16(lo[1]);
    r[2] = cvt_bf16(lo[2]); r[3] = cvt_bf16(lo[3]);
    r[4] = cvt_bf16(hi[0]); r[5] = cvt_bf16(hi[1]);
    r[6] = cvt_bf16(hi[2]); r[7] = cvt_bf16(hi[3]);
    return r;
}

__device__ __forceinline__ void gload16(const void* g, void* s) {
    // async global->LDS, 16B/lane; HW dest = readfirstlane(base) + lane*16
    __builtin_amdgcn_global_load_lds((const __attribute__((address_space(1))) void*)g,
                                     (__attribute__((address_space(3))) void*)s,
                                     16, 0, 0);
}

// ---------------- pre-pass: fp32 -> bf16 bulk convert (f then W1, one launch) ----
__global__ __launch_bounds__(256) void cvt_pass(const float* __restrict__ f,
                                                const float* __restrict__ W1,
                                                __hip_bfloat16* __restrict__ ws) {
    int i = blockIdx.x * 256 + threadIdx.x;
    if (i < C_F8)
        *(bf16x8*)(ws + (size_t)i * 8) = load8_cvt(f + (size_t)i * 8);
    else if (i < C_T8)
        *(bf16x8*)(ws + (size_t)i * 8) = load8_cvt(W1 + ((size_t)i - C_F8) * 8);
}

// ---------------- main fused kernel: 256x128 tile, 4 waves of 64x128 ----------------
// LDS colblock swizzle: data of global (row r, colblock cb) sits at LDS colblock
// cb ^ ((r>>1)&3). Staging keeps li*16 lane-contiguous dest (global_load_lds
// contract); readers get perfect 2-way bank access (free) instead of 8-way.
__global__ __launch_bounds__(256, 2) void fused_heads_bf16(
    const __hip_bfloat16* __restrict__ fb,     // [8192, 384] bf16
    const __hip_bfloat16* __restrict__ W1b,    // [137*128, 384] bf16
    const float* __restrict__ b1,
    const float* __restrict__ gmm,
    const float* __restrict__ bta,
    const float* __restrict__ rmean,
    const float* __restrict__ rvar,
    const float* __restrict__ W2,
    const float* __restrict__ b2,
    float* __restrict__ out)                   // [8192, 137]
{
    __shared__ __attribute__((aligned(16))) __hip_bfloat16 As[256 * 32];  // 16 KB
    __shared__ __attribute__((aligned(16))) __hip_bfloat16 Bs[128 * 32];  //  8 KB

    const int tid  = threadIdx.x;
    const int lane = tid & 63;
    const int wm   = tid >> 6;          // wave = M-slice (0..3), rows wm*64..+64
    const int m0 = blockIdx.x * 256;
    const int t  = blockIdx.y;
    const int n0 = t * KHID;

    const int row16 = lane & 15;
    const int quad  = lane >> 4;
    const int swz   = quad ^ ((row16 >> 1) & 3);   // swizzled k-colblock for reads

    // staging sources: A chunks li = tid + c*256 (c=0..3), B chunks c=0..1
    // chunk li -> LDS bytes li*16; global row r=li>>2, colblock (li&3)^((li>>3)&3)
    const __hip_bfloat16* gA[4];
    const __hip_bfloat16* gB[2];
    #pragma unroll
    for (int c = 0; c < 4; ++c) {
        const int li = tid + c * 256;
        const int r = li >> 2, cb = (li & 3) ^ ((li >> 3) & 3);
        gA[c] = fb + (size_t)(m0 + r) * DFEA + cb * 8;
    }
    #pragma unroll
    for (int c = 0; c < 2; ++c) {
        const int li = tid + c * 256;
        const int r = li >> 2, cb = (li & 3) ^ ((li >> 3) & 3);
        gB[c] = W1b + (size_t)(n0 + r) * DFEA + cb * 8;
    }

    f32x4 acc[4][8];
    #pragma unroll
    for (int i = 0; i < 4; ++i)
        #pragma unroll
        for (int j = 0; j < 8; ++j)
            acc[i][j] = (f32x4){0.f, 0.f, 0.f, 0.f};

    #pragma unroll 1
    for (int kt = 0; kt < DFEA / 32; ++kt) {
        const int k0 = kt * 32;
        #pragma unroll
        for (int c = 0; c < 4; ++c)
            gload16(gA[c] + k0, &As[(tid + c * 256) * 8]);
        #pragma unroll
        for (int c = 0; c < 2; ++c)
            gload16(gB[c] + k0, &Bs[(tid + c * 256) * 8]);
        __syncthreads();   // drains vmcnt -> tiles valid

        bf16x8 af[4], bfr[8];
        #pragma unroll
        for (int ai = 0; ai < 4; ++ai)
            af[ai] = *(const bf16x8*)&As[(wm * 64 + ai * 16 + row16) * 32 + swz * 8];
        #pragma unroll
        for (int bi = 0; bi < 8; ++bi)
            bfr[bi] = *(const bf16x8*)&Bs[(bi * 16 + row16) * 32 + swz * 8];

        #pragma unroll
        for (int ai = 0; ai < 4; ++ai)
            #pragma unroll
            for (int bi = 0; bi < 8; ++bi)
                acc[ai][bi] = __builtin_amdgcn_mfma_f32_16x16x32_bf16(
                    af[ai], bfr[bi], acc[ai][bi], 0, 0, 0);
        __syncthreads();   // all reads done before next overwrite
    }

    // ---- fused epilogue: BN (eval) + LeakyReLU + dot with W2, all in-wave ----
    float s[8], cc[8], w2v[8];
    #pragma unroll
    for (int bi = 0; bi < 8; ++bi) {
        const int n = n0 + bi * 16 + row16;
        const float sv = gmm[n] * rsqrtf(rvar[n] + EPS_BN);
        s[bi]   = sv;
        cc[bi]  = bta[n] + (b1[n] - rmean[n]) * sv;
        w2v[bi] = W2[n];
    }

    float p[4][4];
    #pragma unroll
    for (int ai = 0; ai < 4; ++ai)
        #pragma unroll
        for (int r = 0; r < 4; ++r) {
            float a = 0.f;
            #pragma unroll
            for (int bi = 0; bi < 8; ++bi) {
                float y = acc[ai][bi][r] * s[bi] + cc[bi];
                y = (y >= 0.f) ? y : SLOPE * y;   // LeakyReLU
                a += y * w2v[bi];
            }
            p[ai][r] = a;
        }

    // reduce across the 16 column-lanes (C/D: col = lane&15); masks<16 stay in-quad
    #pragma unroll
    for (int mask = 1; mask <= 8; mask <<= 1)
        #pragma unroll
        for (int ai = 0; ai < 4; ++ai)
            #pragma unroll
            for (int r = 0; r < 4; ++r)
                p[ai][r] += __shfl_xor(p[ai][r], mask);

    if (row16 == 0) {
        const float bias = b2[t];
        #pragma unroll
        for (int ai = 0; ai < 4; ++ai)
            #pragma unroll
            for (int r = 0; r < 4; ++r) {
                const int row = m0 + wm * 64 + ai * 16 + quad * 4 + r;
                out[(size_t)row * THEADS + t] = p[ai][r] + bias;
            }
    }
}

// ---------------- fallback: direct fp32 path (round-3 kernel, 128-tile) ------------
__global__ __launch_bounds__(256) void fused_heads_f32(
    const float* __restrict__ f, const float* __restrict__ W1,
    const float* __restrict__ b1, const float* __restrict__ gmm,
    const float* __restrict__ bta, const float* __restrict__ rmean,
    const float* __restrict__ rvar, const float* __restrict__ W2,
    const float* __restrict__ b2, float* __restrict__ out)
{
    __shared__ __attribute__((aligned(16))) __hip_bfloat16 As[128 * 32];
    __shared__ __attribute__((aligned(16))) __hip_bfloat16 Bs[128 * 32];
    __shared__ float red[2][128];

    const int tid  = threadIdx.x;
    const int lane = tid & 63;
    const int wave = tid >> 6;
    const int wm = wave >> 1, wn = wave & 1;
    const int m0 = blockIdx.x * 128;
    const int t  = blockIdx.y;
    const int n0 = t * KHID;

    const int li0 = tid, li1 = tid + 256;
    const int r0 = li0 >> 2, c0 = (li0 & 3) * 8;
    const int r1 = li1 >> 2, c1 = (li1 & 3) * 8;
    const float* gA0 = f  + (size_t)(m0 + r0) * DFEA + c0;
    const float* gA1 = f  + (size_t)(m0 + r1) * DFEA + c1;
    const float* gB0 = W1 + (size_t)(n0 + r0) * DFEA + c0;
    const float* gB1 = W1 + (size_t)(n0 + r1) * DFEA + c1;

    const int row16 = lane & 15, quad = lane >> 4;

    f32x4 acc[4][4];
    #pragma unroll
    for (int i = 0; i < 4; ++i)
        #pragma unroll
        for (int j = 0; j < 4; ++j)
            acc[i][j] = (f32x4){0.f, 0.f, 0.f, 0.f};

    #pragma unroll 1
    for (int kt = 0; kt < DFEA / 32; ++kt) {
        const int k0 = kt * 32;
        bf16x8 va0 = load8_cvt(gA0 + k0);
        bf16x8 va1 = load8_cvt(gA1 + k0);
        bf16x8 vb0 = load8_cvt(gB0 + k0);
        bf16x8 vb1 = load8_cvt(gB1 + k0);
        __syncthreads();
        *(bf16x8*)&As[li0 * 8] = va0;
        *(bf16x8*)&As[li1 * 8] = va1;
        *(bf16x8*)&Bs[li0 * 8] = vb0;
        *(bf16x8*)&Bs[li1 * 8] = vb1;
        __syncthreads();

        bf16x8 af[4], bfr[4];
        #pragma unroll
        for (int i = 0; i < 4; ++i)
            af[i] = *(const bf16x8*)&As[(wm * 64 + i * 16 + row16) * 32 + quad * 8];
        #pragma unroll
        for (int i = 0; i < 4; ++i)
            bfr[i] = *(const bf16x8*)&Bs[(wn * 64 + i * 16 + row16) * 32 + quad * 8];
        #pragma unroll
        for (int ai = 0; ai < 4; ++ai)
            #pragma unroll
            for (int bi = 0; bi < 4; ++bi)
                acc[ai][bi] = __builtin_amdgcn_mfma_f32_16x16x32_bf16(
                    af[ai], bfr[bi], acc[ai][bi], 0, 0, 0);
    }

    float s[4], cc[4], w2v[4];
    #pragma unroll
    for (int bi = 0; bi < 4; ++bi) {
        const int n = n0 + wn * 64 + bi * 16 + row16;
        const float sv = gmm[n] * rsqrtf(rvar[n] + EPS_BN);
        s[bi] = sv;
        cc[bi] = bta[n] + (b1[n] - rmean[n]) * sv;
        w2v[bi] = W2[n];
    }
    float p[4][4];
    #pragma unroll
    for (int ai = 0; ai < 4; ++ai)
        #pragma unroll
        for (int r = 0; r < 4; ++r) {
            float a = 0.f;
            #pragma unroll
            for (int bi = 0; bi < 4; ++bi) {
                float y = acc[ai][bi][r] * s[bi] + cc[bi];
                y = (y >= 0.f) ? y : SLOPE * y;
                a += y * w2v[bi];
            }
            p[ai][r] = a;
        }
    #pragma unroll
    for (int mask = 1; mask <= 8; mask <<= 1)
        #pragma unroll
        for (int ai = 0; ai < 4; ++ai)
            #pragma unroll
            for (int r = 0; r < 4; ++r)
                p[ai][r] += __shfl_xor(p[ai][r], mask);
    if (row16 == 0) {
        #pragma unroll
        for (int ai = 0; ai < 4; ++ai)
            #pragma unroll
            for (int r = 0; r < 4; ++r)
                red[wn][wm * 64 + ai * 16 + quad * 4 + r] = p[ai][r];
    }
    __syncthreads();
    if (tid < 128)
        out[(size_t)(m0 + tid) * THEADS + t] = red[0][tid] + red[1][tid] + b2[t];
}

extern "C" void kernel_launch(void* const* d_in, const int* in_sizes, int n_in,
                              void* d_out, int out_size, void* d_ws, size_t ws_size,
                              hipStream_t stream) {
    (void)in_sizes; (void)n_in; (void)out_size;
    const float* f     = (const float*)d_in[0];
    const float* W1    = (const float*)d_in[1];
    const float* b1    = (const float*)d_in[2];
    const float* gmm   = (const float*)d_in[3];
    const float* bta   = (const float*)d_in[4];
    const float* rmean = (const float*)d_in[5];
    const float* rvar  = (const float*)d_in[6];
    const float* W2    = (const float*)d_in[7];
    const float* b2    = (const float*)d_in[8];
    float* out = (float*)d_out;

    if (ws_size >= WS_NEED) {
        __hip_bfloat16* fb  = (__hip_bfloat16*)d_ws;
        __hip_bfloat16* W1b = fb + N_F;
        cvt_pass<<<(C_T8 + 255) / 256, 256, 0, stream>>>(f, W1, fb);
        dim3 grid(BATCH / 256, THEADS);
        fused_heads_bf16<<<grid, 256, 0, stream>>>(fb, W1b, b1, gmm, bta, rmean, rvar, W2, b2, out);
    } else {
        dim3 grid(BATCH / 128, THEADS);
        fused_heads_f32<<<grid, 256, 0, stream>>>(f, W1, b1, gmm, bta, rmean, rvar, W2, b2, out);
    }
}